// Round 6
// baseline (459.967 us; speedup 1.0000x reference)
//
#include <hip/hip_runtime.h>
#include <stdint.h>

// IncConv (version==3): out = zeros except 64x64 patch at [48,112)^2 holding
// conv3x3(in, w, pad=1, stride=1) + bias.  B=16, C_in=C_out=64, H=W=224.
//
// Round 6 == Round 5 (never ran: GPU acquisition timeout). Structure:
//   k1 prep_zero : blocks 0..255 zero the 205 MB output (~6.5 TB/s class);
//                  block 256 converts weights to the hi/lo bf16 LDS image
//                  in d_ws (both ci-chunks, 151552 B).
//   k2 conv      : implicit GEMM on bf16 MFMA (3-term hi/lo split).
//                  A staged via b128 ci-run writes (8 dw/bank floor);
//                  B staged as a LINEAR copy of the d_ws image (floor,
//                  no convert VALU). Theory: round-4's 32-way staging-write
//                  conflicts are the missing ~30 us.

#define BATCH 16
#define CI    64
#define CO    64
#define HW    224
#define PR0   48
#define PC0   48

#define THREADS 512
#define NBLK    256

// LDS layout (units: shorts/bf16)
#define A_ROWS 6
#define A_COLS 72                         // global cols 44..115 (f4-aligned)
#define A_CELL 40                         // 32 ci + 8 pad -> 80 B cell
#define A_SIZE (A_ROWS * A_COLS * A_CELL) // 17280 shorts
#define B_KPAD 296                        // 9*32 + 8 pad shorts per n
#define B_HALF (CO * B_KPAD)              // 18944 shorts (one of h/l)
#define B_IMG  (2 * B_HALF)               // 37888 shorts per chunk (h then l)
#define B_F4   (B_IMG / 8)                // 4736 float4 per chunk image
#define LDS_SHORTS (2 * A_SIZE + B_IMG)   // 72448
#define LDS_BYTES  (LDS_SHORTS * 2)       // 144896 B

typedef __attribute__((ext_vector_type(8))) short short8v;
typedef __attribute__((ext_vector_type(4))) float f32x4;

union fu32 { float f; uint32_t u; };

__device__ __forceinline__ uint16_t f2bf(float x) {
    fu32 c; c.f = x;
    return (uint16_t)((c.u + 0x7FFFu + ((c.u >> 16) & 1u)) >> 16);  // RNE
}
__device__ __forceinline__ float bf2f(uint16_t h) {
    fu32 c; c.u = ((uint32_t)h) << 16; return c.f;
}

// ---------------- k1: zero-fill + weight image prep ----------------
__global__ __launch_bounds__(THREADS)
void prep_zero(const float* __restrict__ wgt, float* __restrict__ out,
               unsigned short* __restrict__ ws) {
    const int bid = blockIdx.x;
    const int tid = threadIdx.x;
    if (bid < NBLK) {
        const int NT4 = BATCH * CO * HW * HW / 4;   // 12,845,056 float4
        float4* o4 = (float4*)out;
        const float4 z = make_float4(0.f, 0.f, 0.f, 0.f);
        for (int i = bid * THREADS + tid; i < NT4; i += NBLK * THREADS)
            o4[i] = z;   // full zero; conv overwrites the patch afterwards
        return;
    }
    // block 256: weights -> hi/lo bf16 image, layout [chunk][h|l][n][t*32+cil]
    for (int e = tid; e < CO * CI * 9; e += THREADS) {
        int n   = e / (CI * 9);
        int rem = e - n * (CI * 9);
        int ci  = rem / 9;
        int t   = rem - ci * 9;
        int ch  = ci >> 5;
        int cil = ci & 31;
        float x = wgt[e];
        uint16_t h = f2bf(x);
        uint16_t l = f2bf(x - bf2f(h));
        int idx = ch * B_IMG + n * B_KPAD + t * 32 + cil;
        ws[idx]          = h;
        ws[idx + B_HALF] = l;
    }
}

// ---------------- k2: conv patch (implicit GEMM, bf16 MFMA) ----------------
__global__ __launch_bounds__(THREADS, 1)
void inc_conv_mfma(const float* __restrict__ in,
                   const unsigned short* __restrict__ wsB,
                   const float* __restrict__ bias, float* __restrict__ out) {
    extern __shared__ short smem[];
    short* Ah   = smem;
    short* Al   = smem + A_SIZE;
    short* Bimg = smem + 2 * A_SIZE;      // [h|l][n][t*32+cil]

    const int bid  = blockIdx.x;
    const int tid  = threadIdx.x;
    const int b    = bid >> 4;            // batch
    const int band = bid & 15;            // 4-row band of the 64-row patch

    const int lane = tid & 63;
    const int wv   = tid >> 6;            // wave 0..7
    const int l15  = lane & 15;
    const int kb   = lane >> 4;           // 0..3
    const int prl  = wv >> 1;             // wave's patch row in band (0..3)
    const int pcb  = (wv & 1) << 5;       // wave's patch col base (0 / 32)

    const int gr = PR0 - 1 + (band << 2); // staged input origin row

    // A staging slot: (row ar, col-quad c4, ci-block sb). 432 active slots.
    const int q   = tid < 432 ? tid : 431;
    const int sb  = q & 3;
    const int c4  = (q >> 2) % 18;
    const int ar  = (q >> 2) / 18;
    const bool aAct = tid < 432;

    float bias_v[4];
    #pragma unroll
    for (int nf = 0; nf < 4; ++nf) bias_v[nf] = bias[nf * 16 + l15];

    f32x4 acc[2][4];
    #pragma unroll
    for (int mf = 0; mf < 2; ++mf)
        #pragma unroll
        for (int nf = 0; nf < 4; ++nf)
            acc[mf][nf] = (f32x4){0.f, 0.f, 0.f, 0.f};

    const int aBase = (prl * A_COLS + pcb + l15 + 3) * A_CELL + kb * 8;
    const int bBase = l15 * B_KPAD + kb * 8;

    float4 aR[8], bR[10];

    // ---- load A chunk: 8 float4, one per ci in this thread's ci-block ----
    #define LOAD_A(ci0)                                                        \
        {                                                                      \
            _Pragma("unroll")                                                  \
            for (int j = 0; j < 8; ++j)                                        \
                aR[j] = *(const float4*)&in[((b * CI + (ci0) + sb * 8 + j)     \
                                             * HW + gr + ar) * HW + 44 + 4 * c4]; \
        }

    // ---- load B chunk image: linear float4 copy from d_ws ----
    #define LOAD_B(ch)                                                         \
        {                                                                      \
            const float4* src = (const float4*)(wsB + (ch) * B_IMG);           \
            _Pragma("unroll")                                                  \
            for (int i = 0; i < 10; ++i) {                                     \
                int e = tid + i * THREADS;                                     \
                if (e < B_F4) bR[i] = src[e];                                  \
            }                                                                  \
        }

    // ---- write A: convert, b128 along ci-run (floor-uniform banks) ----
    #define WRITE_A()                                                          \
        if (aAct) {                                                            \
            _Pragma("unroll")                                                  \
            for (int jj = 0; jj < 4; ++jj) {                                   \
                short8v hv, lv;                                                \
                _Pragma("unroll")                                              \
                for (int j = 0; j < 8; ++j) {                                  \
                    float x = aR[j][jj];                                       \
                    uint16_t h = f2bf(x);                                      \
                    uint16_t l = f2bf(x - bf2f(h));                            \
                    hv[j] = (short)h;                                          \
                    lv[j] = (short)l;                                          \
                }                                                              \
                int cell = ar * A_COLS + 4 * c4 + jj;                          \
                *(short8v*)(Ah + cell * A_CELL + sb * 8) = hv;                 \
                *(short8v*)(Al + cell * A_CELL + sb * 8) = lv;                 \
            }                                                                  \
        }

    // ---- write B: linear b128 (floor-uniform, no convert) ----
    #define WRITE_B()                                                          \
        {                                                                      \
            _Pragma("unroll")                                                  \
            for (int i = 0; i < 10; ++i) {                                     \
                int e = tid + i * THREADS;                                     \
                if (e < B_F4) *(float4*)(Bimg + e * 8) = bR[i];                \
            }                                                                  \
        }

    // ---- MFMA over 9 taps for one staged chunk ----
    #define COMPUTE_CHUNK()                                                    \
        {                                                                      \
            _Pragma("unroll")                                                  \
            for (int t = 0; t < 9; ++t) {                                      \
                const int kh = t / 3, kw = t - kh * 3;                         \
                short8v ah[2], al[2], bh[4], bl[4];                            \
                _Pragma("unroll")                                              \
                for (int mf = 0; mf < 2; ++mf) {                               \
                    const int off = aBase + (kh * A_COLS + mf * 16 + kw) * A_CELL; \
                    ah[mf] = *(const short8v*)(Ah + off);                      \
                    al[mf] = *(const short8v*)(Al + off);                      \
                }                                                              \
                _Pragma("unroll")                                              \
                for (int nf = 0; nf < 4; ++nf) {                               \
                    const int off = bBase + nf * 16 * B_KPAD + t * 32;         \
                    bh[nf] = *(const short8v*)(Bimg + off);                    \
                    bl[nf] = *(const short8v*)(Bimg + B_HALF + off);           \
                }                                                              \
                _Pragma("unroll")                                              \
                for (int mf = 0; mf < 2; ++mf)                                 \
                    _Pragma("unroll")                                          \
                    for (int nf = 0; nf < 4; ++nf) {                           \
                        acc[mf][nf] = __builtin_amdgcn_mfma_f32_16x16x32_bf16( \
                            ah[mf], bh[nf], acc[mf][nf], 0, 0, 0);             \
                        acc[mf][nf] = __builtin_amdgcn_mfma_f32_16x16x32_bf16( \
                            ah[mf], bl[nf], acc[mf][nf], 0, 0, 0);             \
                        acc[mf][nf] = __builtin_amdgcn_mfma_f32_16x16x32_bf16( \
                            al[mf], bh[nf], acc[mf][nf], 0, 0, 0);             \
                    }                                                          \
            }                                                                  \
        }

    // ---- software pipeline over the 2 ci-chunks ----
    LOAD_A(0); LOAD_B(0);
    WRITE_A(); WRITE_B();
    __syncthreads();
    LOAD_A(32); LOAD_B(1);   // chunk-1 loads in flight during compute-0
    COMPUTE_CHUNK();
    __syncthreads();         // chunk-0 readers done
    WRITE_A(); WRITE_B();    // load waits hidden under compute-0
    __syncthreads();
    COMPUTE_CHUNK();

    // ---- epilogue: C/D col=lane&15 (co), row=kb*4+reg (patch col) ----
    const int orow = PR0 + (band << 2) + prl;
    #pragma unroll
    for (int nf = 0; nf < 4; ++nf) {
        const int co = nf * 16 + l15;
        const float bv = bias_v[nf];
        #pragma unroll
        for (int mf = 0; mf < 2; ++mf) {
            const int ocol = PC0 + pcb + mf * 16 + kb * 4;
            f32x4 v = acc[mf][nf];
            float4 st = make_float4(v[0] + bv, v[1] + bv, v[2] + bv, v[3] + bv);
            *(float4*)&out[((b * CO + co) * HW + orow) * HW + ocol] = st;
        }
    }
}

extern "C" void kernel_launch(void* const* d_in, const int* in_sizes, int n_in,
                              void* d_out, int out_size, void* d_ws, size_t ws_size,
                              hipStream_t stream) {
    const float* in   = (const float*)d_in[0];
    const float* wgt  = (const float*)d_in[1];
    const float* bias = (const float*)d_in[2];
    float* out = (float*)d_out;
    unsigned short* ws = (unsigned short*)d_ws;   // needs 2*B_IMG*2 = 151552 B

    prep_zero<<<NBLK + 1, THREADS, 0, stream>>>(wgt, out, ws);

    hipFuncSetAttribute((const void*)inc_conv_mfma,
                        hipFuncAttributeMaxDynamicSharedMemorySize, LDS_BYTES);
    inc_conv_mfma<<<NBLK, THREADS, LDS_BYTES, stream>>>(in, ws, bias, out);
}

// Round 9
// 425.044 us; speedup vs baseline: 1.0822x; 1.0822x over previous
//
#include <hip/hip_runtime.h>
#include <stdint.h>

// IncConv (version==3): out = zeros except 64x64 patch at [48,112)^2 holding
// conv3x3(in, w, pad=1, stride=1) + bias.  B=16, C_in=C_out=64, H=W=224.
//
// Round 9 == Round 7/8 (never ran: GPU acquisition timeouts). Structure:
//   k0 prep_b  : weights -> hi/lo bf16 LDS image in d_ws (144 blocks, ~2 us).
//   k1 memset  : hipMemsetAsync zeroes output (rocclr fill, measured 6.7 TB/s).
//   k2 conv    : implicit GEMM on bf16 MFMA (3-term hi/lo split), UNCHANGED
//                from round 6: A staged via b128 ci-run writes (bank floor),
//                B staged as linear copy of the d_ws image (bank floor).

#define BATCH 16
#define CI    64
#define CO    64
#define HW    224
#define PR0   48
#define PC0   48

#define THREADS 512
#define NBLK    256

// LDS layout (units: shorts/bf16)
#define A_ROWS 6
#define A_COLS 72                         // global cols 44..115 (f4-aligned)
#define A_CELL 40                         // 32 ci + 8 pad -> 80 B cell
#define A_SIZE (A_ROWS * A_COLS * A_CELL) // 17280 shorts
#define B_KPAD 296                        // 9*32 + 8 pad shorts per n
#define B_HALF (CO * B_KPAD)              // 18944 shorts (one of h/l)
#define B_IMG  (2 * B_HALF)               // 37888 shorts per chunk (h then l)
#define B_F4   (B_IMG / 8)                // 4736 float4 per chunk image
#define LDS_SHORTS (2 * A_SIZE + B_IMG)   // 72448
#define LDS_BYTES  (LDS_SHORTS * 2)       // 144896 B

typedef __attribute__((ext_vector_type(8))) short short8v;
typedef __attribute__((ext_vector_type(4))) float f32x4;

union fu32 { float f; uint32_t u; };

__device__ __forceinline__ uint16_t f2bf(float x) {
    fu32 c; c.f = x;
    return (uint16_t)((c.u + 0x7FFFu + ((c.u >> 16) & 1u)) >> 16);  // RNE
}
__device__ __forceinline__ float bf2f(uint16_t h) {
    fu32 c; c.u = ((uint32_t)h) << 16; return c.f;
}

// ---------------- k0: weight image prep (one element per thread) ----------------
__global__ __launch_bounds__(256)
void prep_b(const float* __restrict__ wgt, unsigned short* __restrict__ ws) {
    const int e = blockIdx.x * 256 + threadIdx.x;   // 144 blocks -> e < 36864
    int n   = e / (CI * 9);
    int rem = e - n * (CI * 9);
    int ci  = rem / 9;
    int t   = rem - ci * 9;
    int ch  = ci >> 5;
    int cil = ci & 31;
    float x = wgt[e];
    uint16_t h = f2bf(x);
    uint16_t l = f2bf(x - bf2f(h));
    int idx = ch * B_IMG + n * B_KPAD + t * 32 + cil;
    ws[idx]          = h;
    ws[idx + B_HALF] = l;
}

// ---------------- k2: conv patch (implicit GEMM, bf16 MFMA) ----------------
__global__ __launch_bounds__(THREADS, 1)
void inc_conv_mfma(const float* __restrict__ in,
                   const unsigned short* __restrict__ wsB,
                   const float* __restrict__ bias, float* __restrict__ out) {
    extern __shared__ short smem[];
    short* Ah   = smem;
    short* Al   = smem + A_SIZE;
    short* Bimg = smem + 2 * A_SIZE;      // [h|l][n][t*32+cil]

    const int bid  = blockIdx.x;
    const int tid  = threadIdx.x;
    const int b    = bid >> 4;            // batch
    const int band = bid & 15;            // 4-row band of the 64-row patch

    const int lane = tid & 63;
    const int wv   = tid >> 6;            // wave 0..7
    const int l15  = lane & 15;
    const int kb   = lane >> 4;           // 0..3
    const int prl  = wv >> 1;             // wave's patch row in band (0..3)
    const int pcb  = (wv & 1) << 5;       // wave's patch col base (0 / 32)

    const int gr = PR0 - 1 + (band << 2); // staged input origin row

    // A staging slot: (row ar, col-quad c4, ci-block sb). 432 active slots.
    const int q   = tid < 432 ? tid : 431;
    const int sb  = q & 3;
    const int c4  = (q >> 2) % 18;
    const int ar  = (q >> 2) / 18;
    const bool aAct = tid < 432;

    float bias_v[4];
    #pragma unroll
    for (int nf = 0; nf < 4; ++nf) bias_v[nf] = bias[nf * 16 + l15];

    f32x4 acc[2][4];
    #pragma unroll
    for (int mf = 0; mf < 2; ++mf)
        #pragma unroll
        for (int nf = 0; nf < 4; ++nf)
            acc[mf][nf] = (f32x4){0.f, 0.f, 0.f, 0.f};

    const int aBase = (prl * A_COLS + pcb + l15 + 3) * A_CELL + kb * 8;
    const int bBase = l15 * B_KPAD + kb * 8;

    float4 aR[8], bR[10];

    // ---- load A chunk: 8 float4, one per ci in this thread's ci-block ----
    #define LOAD_A(ci0)                                                        \
        {                                                                      \
            _Pragma("unroll")                                                  \
            for (int j = 0; j < 8; ++j)                                        \
                aR[j] = *(const float4*)&in[((b * CI + (ci0) + sb * 8 + j)     \
                                             * HW + gr + ar) * HW + 44 + 4 * c4]; \
        }

    // ---- load B chunk image: linear float4 copy from d_ws ----
    #define LOAD_B(ch)                                                         \
        {                                                                      \
            const float4* src = (const float4*)(wsB + (ch) * B_IMG);           \
            _Pragma("unroll")                                                  \
            for (int i = 0; i < 10; ++i) {                                     \
                int e = tid + i * THREADS;                                     \
                if (e < B_F4) bR[i] = src[e];                                  \
            }                                                                  \
        }

    // ---- write A: convert, b128 along ci-run (floor-uniform banks) ----
    #define WRITE_A()                                                          \
        if (aAct) {                                                            \
            _Pragma("unroll")                                                  \
            for (int jj = 0; jj < 4; ++jj) {                                   \
                short8v hv, lv;                                                \
                _Pragma("unroll")                                              \
                for (int j = 0; j < 8; ++j) {                                  \
                    float x = aR[j][jj];                                       \
                    uint16_t h = f2bf(x);                                      \
                    uint16_t l = f2bf(x - bf2f(h));                            \
                    hv[j] = (short)h;                                          \
                    lv[j] = (short)l;                                          \
                }                                                              \
                int cell = ar * A_COLS + 4 * c4 + jj;                          \
                *(short8v*)(Ah + cell * A_CELL + sb * 8) = hv;                 \
                *(short8v*)(Al + cell * A_CELL + sb * 8) = lv;                 \
            }                                                                  \
        }

    // ---- write B: linear b128 (floor-uniform, no convert) ----
    #define WRITE_B()                                                          \
        {                                                                      \
            _Pragma("unroll")                                                  \
            for (int i = 0; i < 10; ++i) {                                     \
                int e = tid + i * THREADS;                                     \
                if (e < B_F4) *(float4*)(Bimg + e * 8) = bR[i];                \
            }                                                                  \
        }

    // ---- MFMA over 9 taps for one staged chunk ----
    #define COMPUTE_CHUNK()                                                    \
        {                                                                      \
            _Pragma("unroll")                                                  \
            for (int t = 0; t < 9; ++t) {                                      \
                const int kh = t / 3, kw = t - kh * 3;                         \
                short8v ah[2], al[2], bh[4], bl[4];                            \
                _Pragma("unroll")                                              \
                for (int mf = 0; mf < 2; ++mf) {                               \
                    const int off = aBase + (kh * A_COLS + mf * 16 + kw) * A_CELL; \
                    ah[mf] = *(const short8v*)(Ah + off);                      \
                    al[mf] = *(const short8v*)(Al + off);                      \
                }                                                              \
                _Pragma("unroll")                                              \
                for (int nf = 0; nf < 4; ++nf) {                               \
                    const int off = bBase + nf * 16 * B_KPAD + t * 32;         \
                    bh[nf] = *(const short8v*)(Bimg + off);                    \
                    bl[nf] = *(const short8v*)(Bimg + B_HALF + off);           \
                }                                                              \
                _Pragma("unroll")                                              \
                for (int mf = 0; mf < 2; ++mf)                                 \
                    _Pragma("unroll")                                          \
                    for (int nf = 0; nf < 4; ++nf) {                           \
                        acc[mf][nf] = __builtin_amdgcn_mfma_f32_16x16x32_bf16( \
                            ah[mf], bh[nf], acc[mf][nf], 0, 0, 0);             \
                        acc[mf][nf] = __builtin_amdgcn_mfma_f32_16x16x32_bf16( \
                            ah[mf], bl[nf], acc[mf][nf], 0, 0, 0);             \
                        acc[mf][nf] = __builtin_amdgcn_mfma_f32_16x16x32_bf16( \
                            al[mf], bh[nf], acc[mf][nf], 0, 0, 0);             \
                    }                                                          \
            }                                                                  \
        }

    // ---- software pipeline over the 2 ci-chunks ----
    LOAD_A(0); LOAD_B(0);
    WRITE_A(); WRITE_B();
    __syncthreads();
    LOAD_A(32); LOAD_B(1);   // chunk-1 loads in flight during compute-0
    COMPUTE_CHUNK();
    __syncthreads();         // chunk-0 readers done
    WRITE_A(); WRITE_B();    // load waits hidden under compute-0
    __syncthreads();
    COMPUTE_CHUNK();

    // ---- epilogue: C/D col=lane&15 (co), row=kb*4+reg (patch col) ----
    const int orow = PR0 + (band << 2) + prl;
    #pragma unroll
    for (int nf = 0; nf < 4; ++nf) {
        const int co = nf * 16 + l15;
        const float bv = bias_v[nf];
        #pragma unroll
        for (int mf = 0; mf < 2; ++mf) {
            const int ocol = PC0 + pcb + mf * 16 + kb * 4;
            f32x4 v = acc[mf][nf];
            float4 st = make_float4(v[0] + bv, v[1] + bv, v[2] + bv, v[3] + bv);
            *(float4*)&out[((b * CO + co) * HW + orow) * HW + ocol] = st;
        }
    }
}

extern "C" void kernel_launch(void* const* d_in, const int* in_sizes, int n_in,
                              void* d_out, int out_size, void* d_ws, size_t ws_size,
                              hipStream_t stream) {
    const float* in   = (const float*)d_in[0];
    const float* wgt  = (const float*)d_in[1];
    const float* bias = (const float*)d_in[2];
    float* out = (float*)d_out;
    unsigned short* ws = (unsigned short*)d_ws;   // needs 2*B_IMG*2 = 151552 B

    // k0: weight image (CO*CI*9 = 36864 elements, one per thread)
    prep_b<<<144, 256, 0, stream>>>(wgt, ws);

    // k1: zero the whole output at rocclr-fill bandwidth (capture-safe)
    hipMemsetAsync(out, 0, (size_t)out_size * sizeof(float), stream);

    // k2: conv patch kernel
    hipFuncSetAttribute((const void*)inc_conv_mfma,
                        hipFuncAttributeMaxDynamicSharedMemorySize, LDS_BYTES);
    inc_conv_mfma<<<NBLK, THREADS, LDS_BYTES, stream>>>(in, ws, bias, out);
}